// Round 1
// baseline (312.779 us; speedup 1.0000x reference)
//
#include <hip/hip_runtime.h>
#include <hip/hip_bf16.h>
#include <stdint.h>

#define T_TOK 2048
#define DIM 1024
#define FDIM 2048
#define NEXP 8
#define NSLOT 4096

typedef short bf16x8 __attribute__((ext_vector_type(8)));
typedef float f32x4 __attribute__((ext_vector_type(4)));

__device__ __forceinline__ unsigned short f2bf(float f) {
  union { float f; unsigned int u; } v; v.f = f;
  unsigned int r = v.u + 0x7FFFu + ((v.u >> 16) & 1u);
  return (unsigned short)(r >> 16);
}

__device__ __forceinline__ void gld_lds16(const void* g, void* l) {
  __builtin_amdgcn_global_load_lds(
      (const __attribute__((address_space(1))) unsigned int*)g,
      (__attribute__((address_space(3))) unsigned int*)l, 16, 0, 0);
}

// ---------------- Router: fp32 exact, one wave per token ----------------
__global__ void router_kernel(const float* __restrict__ x, const float* __restrict__ rk,
                              int* __restrict__ counts, int* __restrict__ tok_e,
                              float* __restrict__ tok_w) {
  int w = threadIdx.x >> 6, lane = threadIdx.x & 63;
  int t = blockIdx.x * 4 + w;
  float acc[NEXP];
#pragma unroll
  for (int e = 0; e < NEXP; ++e) acc[e] = 0.f;
  const float4* xr = (const float4*)(x + (size_t)t * DIM);
#pragma unroll
  for (int i = 0; i < 4; ++i) {
    float4 xv = xr[i * 64 + lane];
    int d0 = (i * 64 + lane) * 4;
#pragma unroll
    for (int j = 0; j < 4; ++j) {
      const float4* rr = (const float4*)(rk + (size_t)(d0 + j) * NEXP);
      float4 r0 = rr[0], r1 = rr[1];
      float xs = (j == 0) ? xv.x : (j == 1) ? xv.y : (j == 2) ? xv.z : xv.w;
      acc[0] += xs * r0.x; acc[1] += xs * r0.y; acc[2] += xs * r0.z; acc[3] += xs * r0.w;
      acc[4] += xs * r1.x; acc[5] += xs * r1.y; acc[6] += xs * r1.z; acc[7] += xs * r1.w;
    }
  }
#pragma unroll
  for (int off = 32; off > 0; off >>= 1) {
#pragma unroll
    for (int e = 0; e < NEXP; ++e) acc[e] += __shfl_xor(acc[e], off, 64);
  }
  if (lane == 0) {
    float m = acc[0];
    for (int e = 1; e < NEXP; ++e) m = fmaxf(m, acc[e]);
    float p[NEXP], s = 0.f;
    for (int e = 0; e < NEXP; ++e) { p[e] = expf(acc[e] - m); s += p[e]; }
    float inv = 1.f / s;
    for (int e = 0; e < NEXP; ++e) p[e] *= inv;
    int i1 = 0;
    for (int e = 1; e < NEXP; ++e) if (p[e] > p[i1]) i1 = e;      // ties -> lowest idx
    int i2 = (i1 == 0) ? 1 : 0;
    for (int e = 0; e < NEXP; ++e) if (e != i1 && p[e] > p[i2]) i2 = e;
    // reference: softmax over the two top PROBABILITIES
    float e1 = expf(p[i1]), e2 = expf(p[i2]);
    float winv = 1.f / (e1 + e2);
    tok_e[t * 2] = i1; tok_e[t * 2 + 1] = i2;
    tok_w[t * 2] = e1 * winv; tok_w[t * 2 + 1] = e2 * winv;
    atomicAdd(&counts[i1], 1); atomicAdd(&counts[i2], 1);
  }
}

__global__ void scan_kernel(const int* __restrict__ counts, int* __restrict__ offsets) {
  if (threadIdx.x == 0) {
    int s = 0;
    for (int e = 0; e < NEXP; ++e) { offsets[e] = s; s += counts[e]; }
  }
}

__global__ void assign_kernel(const int* __restrict__ tok_e, const float* __restrict__ tok_w,
                              const int* __restrict__ offsets, int* __restrict__ cursor,
                              int* __restrict__ slot_token, float* __restrict__ slot_weight,
                              int* __restrict__ tok_slot) {
  int t = blockIdx.x * 256 + threadIdx.x;
  if (t >= T_TOK) return;
#pragma unroll
  for (int k = 0; k < 2; ++k) {
    int e = tok_e[t * 2 + k];
    int pos = atomicAdd(&cursor[e], 1);
    int slot = offsets[e] + pos;
    slot_token[slot] = t;
    slot_weight[slot] = tok_w[t * 2 + k];
    tok_slot[t * 2 + k] = slot;
  }
}

// ---------------- Conversions ----------------
__global__ void cvt_x_kernel(const float* __restrict__ x, unsigned short* __restrict__ xb) {
  int i = blockIdx.x * 256 + threadIdx.x;  // T*D/8 threads
  const float4* p = (const float4*)x;
  float4 a = p[i * 2], b = p[i * 2 + 1];
  uint4 o;
  o.x = ((unsigned)f2bf(a.y) << 16) | f2bf(a.x);
  o.y = ((unsigned)f2bf(a.w) << 16) | f2bf(a.z);
  o.z = ((unsigned)f2bf(b.y) << 16) | f2bf(b.x);
  o.w = ((unsigned)f2bf(b.w) << 16) | f2bf(b.z);
  ((uint4*)xb)[i] = o;
}

// in fp32 [E][R][C] -> out bf16 [E][C][R]
__global__ void transpose_cvt_kernel(const float* __restrict__ in, unsigned short* __restrict__ out,
                                     int R, int C) {
  __shared__ float lds[64][65];
  int e = blockIdx.z;
  size_t base = (size_t)e * (size_t)R * (size_t)C;
  int rb = blockIdx.y * 64, cb = blockIdx.x * 64;
  int tid = threadIdx.x;
  int col4 = (tid & 15) * 4, row = tid >> 4;
#pragma unroll
  for (int it = 0; it < 4; ++it) {
    int r = row + it * 16;
    float4 v = *(const float4*)(in + base + (size_t)(rb + r) * C + cb + col4);
    lds[col4 + 0][r] = v.x; lds[col4 + 1][r] = v.y;
    lds[col4 + 2][r] = v.z; lds[col4 + 3][r] = v.w;
  }
  __syncthreads();
  int r2 = (tid & 31) * 2, c = tid >> 5;
#pragma unroll
  for (int it = 0; it < 8; ++it) {
    int cc = c + it * 8;
    unsigned v = ((unsigned)f2bf(lds[cc][r2 + 1]) << 16) | f2bf(lds[cc][r2]);
    *(unsigned*)(out + base + (size_t)(cb + cc) * R + rb + r2) = v;
  }
}

// ---------------- Pass A: fuse[slot][F] = silu(X@Wg) * (X@Wu), grouped per expert ----------------
__global__ __launch_bounds__(256) void gemm_gateup(
    const unsigned short* __restrict__ xb, const unsigned short* __restrict__ wg,
    const unsigned short* __restrict__ wu, const int* __restrict__ counts,
    const int* __restrict__ offsets, const int* __restrict__ slot_token,
    unsigned short* __restrict__ fuse) {
  int e = blockIdx.z;
  int cnt = counts[e];
  int mt = blockIdx.y;
  if (mt * 128 >= cnt) return;
  int off = offsets[e];
  int nt = blockIdx.x;
  __shared__ unsigned short Al[128 * 64];
  __shared__ unsigned short Bgl[128 * 64];
  __shared__ unsigned short Bul[128 * 64];
  int tid = threadIdx.x, w = tid >> 6, lane = tid & 63;
  int w4 = w * 4;
  const unsigned short* asrc[4];
  const unsigned short* bgsrc[4];
  const unsigned short* busrc[4];
#pragma unroll
  for (int ii = 0; ii < 4; ++ii) {
    int i = w4 + ii;
    int r = i * 8 + (lane >> 3);
    int row = mt * 128 + r;
    int tok = (row < cnt) ? slot_token[off + row] : 0;  // clamp: garbage rows computed, not written
    asrc[ii] = xb + (size_t)tok * DIM + (lane & 7) * 8;
    size_t frow = (size_t)e * FDIM + (size_t)(nt * 128 + r);
    bgsrc[ii] = wg + frow * DIM + (lane & 7) * 8;
    busrc[ii] = wu + frow * DIM + (lane & 7) * 8;
  }
  f32x4 accg[4][4] = {};
  f32x4 accu[4][4] = {};
  int wr = (w >> 1) * 64, wc = (w & 1) * 64;
  for (int k0 = 0; k0 < DIM; k0 += 64) {
#pragma unroll
    for (int ii = 0; ii < 4; ++ii) {
      int i = w4 + ii;
      gld_lds16(asrc[ii] + k0, &Al[i * 512]);
      gld_lds16(bgsrc[ii] + k0, &Bgl[i * 512]);
      gld_lds16(busrc[ii] + k0, &Bul[i * 512]);
    }
    __syncthreads();
#pragma unroll
    for (int kk = 0; kk < 2; ++kk) {
      int kof = kk * 32 + (lane >> 4) * 8;
      bf16x8 af[4], bg[4], bu[4];
#pragma unroll
      for (int q = 0; q < 4; ++q) {
        af[q] = *(const bf16x8*)&Al[(wr + q * 16 + (lane & 15)) * 64 + kof];
        bg[q] = *(const bf16x8*)&Bgl[(wc + q * 16 + (lane & 15)) * 64 + kof];
        bu[q] = *(const bf16x8*)&Bul[(wc + q * 16 + (lane & 15)) * 64 + kof];
      }
#pragma unroll
      for (int m4 = 0; m4 < 4; ++m4) {
#pragma unroll
        for (int n4 = 0; n4 < 4; ++n4) {
          accg[m4][n4] = __builtin_amdgcn_mfma_f32_16x16x32_bf16(af[m4], bg[n4], accg[m4][n4], 0, 0, 0);
          accu[m4][n4] = __builtin_amdgcn_mfma_f32_16x16x32_bf16(af[m4], bu[n4], accu[m4][n4], 0, 0, 0);
        }
      }
    }
    __syncthreads();
  }
#pragma unroll
  for (int m4 = 0; m4 < 4; ++m4) {
#pragma unroll
    for (int n4 = 0; n4 < 4; ++n4) {
      f32x4 g = accg[m4][n4], u = accu[m4][n4];
#pragma unroll
      for (int j = 0; j < 4; ++j) {
        int r = wr + m4 * 16 + (lane >> 4) * 4 + j;  // C layout: row=(lane>>4)*4+reg
        int row = mt * 128 + r;
        if (row < cnt) {
          float gv = g[j];
          float val = gv / (1.f + expf(-gv)) * u[j];
          int f = nt * 128 + wc + n4 * 16 + (lane & 15);  // col=lane&15
          fuse[(size_t)(off + row) * FDIM + f] = f2bf(val);
        }
      }
    }
  }
}

// ---------------- Pass B: part[slot][D] = w_slot * (fuse @ WdT) ----------------
__global__ __launch_bounds__(256) void gemm_down(
    const unsigned short* __restrict__ fuse, const unsigned short* __restrict__ wd,
    const int* __restrict__ counts, const int* __restrict__ offsets,
    const float* __restrict__ slot_weight, float* __restrict__ part) {
  int e = blockIdx.z;
  int cnt = counts[e];
  int mt = blockIdx.y;
  if (mt * 128 >= cnt) return;
  int off = offsets[e];
  int nt = blockIdx.x;  // over D/128 = 8
  __shared__ unsigned short Al[128 * 64];
  __shared__ unsigned short Bl[128 * 64];
  int tid = threadIdx.x, w = tid >> 6, lane = tid & 63;
  int w4 = w * 4;
  const unsigned short* asrc[4];
  const unsigned short* bsrc[4];
#pragma unroll
  for (int ii = 0; ii < 4; ++ii) {
    int i = w4 + ii;
    int r = i * 8 + (lane >> 3);
    int row = mt * 128 + r;
    int grow = (row < cnt) ? (off + row) : off;  // clamp to valid memory
    asrc[ii] = fuse + (size_t)grow * FDIM + (lane & 7) * 8;
    size_t drow = (size_t)e * DIM + (size_t)(nt * 128 + r);
    bsrc[ii] = wd + drow * FDIM + (lane & 7) * 8;
  }
  f32x4 acc[4][4] = {};
  int wr = (w >> 1) * 64, wc = (w & 1) * 64;
  for (int k0 = 0; k0 < FDIM; k0 += 64) {
#pragma unroll
    for (int ii = 0; ii < 4; ++ii) {
      int i = w4 + ii;
      gld_lds16(asrc[ii] + k0, &Al[i * 512]);
      gld_lds16(bsrc[ii] + k0, &Bl[i * 512]);
    }
    __syncthreads();
#pragma unroll
    for (int kk = 0; kk < 2; ++kk) {
      int kof = kk * 32 + (lane >> 4) * 8;
      bf16x8 af[4], bfr[4];
#pragma unroll
      for (int q = 0; q < 4; ++q) {
        af[q] = *(const bf16x8*)&Al[(wr + q * 16 + (lane & 15)) * 64 + kof];
        bfr[q] = *(const bf16x8*)&Bl[(wc + q * 16 + (lane & 15)) * 64 + kof];
      }
#pragma unroll
      for (int m4 = 0; m4 < 4; ++m4) {
#pragma unroll
        for (int n4 = 0; n4 < 4; ++n4) {
          acc[m4][n4] = __builtin_amdgcn_mfma_f32_16x16x32_bf16(af[m4], bfr[n4], acc[m4][n4], 0, 0, 0);
        }
      }
    }
    __syncthreads();
  }
#pragma unroll
  for (int m4 = 0; m4 < 4; ++m4) {
#pragma unroll
    for (int j = 0; j < 4; ++j) {
      int r = wr + m4 * 16 + (lane >> 4) * 4 + j;
      int row = mt * 128 + r;
      if (row < cnt) {
        float wgt = slot_weight[off + row];
#pragma unroll
        for (int n4 = 0; n4 < 4; ++n4) {
          int d = nt * 128 + wc + n4 * 16 + (lane & 15);
          part[(size_t)(off + row) * DIM + d] = acc[m4][n4][j] * wgt;
        }
      }
    }
  }
}

// ---------------- Combine: out[t] = part[slot0] + part[slot1] ----------------
__global__ void combine_kernel(const float* __restrict__ part, const int* __restrict__ tok_slot,
                               float* __restrict__ out) {
  int i = blockIdx.x * 256 + threadIdx.x;  // T*D/4 threads
  int t = i >> 8;
  int c = i & 255;
  int s0 = tok_slot[t * 2], s1 = tok_slot[t * 2 + 1];
  float4 a = ((const float4*)(part + (size_t)s0 * DIM))[c];
  float4 b = ((const float4*)(part + (size_t)s1 * DIM))[c];
  float4 o;
  o.x = a.x + b.x; o.y = a.y + b.y; o.z = a.z + b.z; o.w = a.w + b.w;
  ((float4*)(out + (size_t)t * DIM))[c] = o;
}

extern "C" void kernel_launch(void* const* d_in, const int* in_sizes, int n_in,
                              void* d_out, int out_size, void* d_ws, size_t ws_size,
                              hipStream_t stream) {
  (void)in_sizes; (void)n_in; (void)out_size;
  const float* x    = (const float*)d_in[0];
  const float* rk   = (const float*)d_in[1];
  const float* wg_f = (const float*)d_in[2];
  const float* wu_f = (const float*)d_in[3];
  const float* wd_f = (const float*)d_in[4];
  float* out = (float*)d_out;

  char* ws = (char*)d_ws;
  size_t o_xb   = 0;
  size_t o_wg   = o_xb + (size_t)T_TOK * DIM * 2;
  size_t o_wu   = o_wg + (size_t)NEXP * FDIM * DIM * 2;
  size_t o_wd   = o_wu + (size_t)NEXP * FDIM * DIM * 2;
  size_t o_fuse = o_wd + (size_t)NEXP * DIM * FDIM * 2;
  size_t o_part = o_fuse + (size_t)NSLOT * FDIM * 2;
  size_t o_meta = o_part + (size_t)NSLOT * DIM * 4;
  size_t o_counts = o_meta;
  size_t o_cursor = o_counts + 32;
  size_t o_offs   = o_cursor + 32;
  size_t o_tok_e  = o_offs + 32;
  size_t o_tok_w  = o_tok_e + (size_t)T_TOK * 2 * 4;
  size_t o_tok_s  = o_tok_w + (size_t)T_TOK * 2 * 4;
  size_t o_st     = o_tok_s + (size_t)T_TOK * 2 * 4;
  size_t o_sw     = o_st + (size_t)NSLOT * 4;
  size_t need     = o_sw + (size_t)NSLOT * 4;
  if (ws_size < need) return;  // diagnostic: absmax will equal ~0.785 (zero output)

  unsigned short* xb   = (unsigned short*)(ws + o_xb);
  unsigned short* wgt  = (unsigned short*)(ws + o_wg);
  unsigned short* wut  = (unsigned short*)(ws + o_wu);
  unsigned short* wdt  = (unsigned short*)(ws + o_wd);
  unsigned short* fuse = (unsigned short*)(ws + o_fuse);
  float* part          = (float*)(ws + o_part);
  int* counts          = (int*)(ws + o_counts);
  int* cursor          = (int*)(ws + o_cursor);
  int* offsets         = (int*)(ws + o_offs);
  int* tok_e           = (int*)(ws + o_tok_e);
  float* tok_w         = (float*)(ws + o_tok_w);
  int* tok_slot        = (int*)(ws + o_tok_s);
  int* slot_token      = (int*)(ws + o_st);
  float* slot_weight   = (float*)(ws + o_sw);

  hipMemsetAsync(ws + o_counts, 0, 64, stream);  // counts + cursor
  router_kernel<<<T_TOK / 4, 256, 0, stream>>>(x, rk, counts, tok_e, tok_w);
  scan_kernel<<<1, 64, 0, stream>>>(counts, offsets);
  assign_kernel<<<T_TOK / 256, 256, 0, stream>>>(tok_e, tok_w, offsets, cursor,
                                                 slot_token, slot_weight, tok_slot);
  cvt_x_kernel<<<(T_TOK * DIM / 8) / 256, 256, 0, stream>>>(x, xb);
  transpose_cvt_kernel<<<dim3(FDIM / 64, DIM / 64, NEXP), 256, 0, stream>>>(wg_f, wgt, DIM, FDIM);
  transpose_cvt_kernel<<<dim3(FDIM / 64, DIM / 64, NEXP), 256, 0, stream>>>(wu_f, wut, DIM, FDIM);
  transpose_cvt_kernel<<<dim3(DIM / 64, FDIM / 64, NEXP), 256, 0, stream>>>(wd_f, wdt, FDIM, DIM);
  gemm_gateup<<<dim3(FDIM / 128, 16, NEXP), 256, 0, stream>>>(xb, wgt, wut, counts, offsets,
                                                              slot_token, fuse);
  gemm_down<<<dim3(DIM / 128, 16, NEXP), 256, 0, stream>>>(fuse, wdt, counts, offsets,
                                                           slot_weight, part);
  combine_kernel<<<(T_TOK * DIM / 4) / 256, 256, 0, stream>>>(part, tok_slot, out);
}

// Round 2
// 288.072 us; speedup vs baseline: 1.0858x; 1.0858x over previous
//
#include <hip/hip_runtime.h>
#include <hip/hip_bf16.h>
#include <stdint.h>

#define T_TOK 2048
#define DIM 1024
#define FDIM 2048
#define NEXP 8
#define NSLOT 4096

typedef short bf16x8 __attribute__((ext_vector_type(8)));
typedef float f32x4 __attribute__((ext_vector_type(4)));

__device__ __forceinline__ unsigned short f2bf(float f) {
  union { float f; unsigned int u; } v; v.f = f;
  unsigned int r = v.u + 0x7FFFu + ((v.u >> 16) & 1u);
  return (unsigned short)(r >> 16);
}

__device__ __forceinline__ void gld_lds16(const void* g, void* l) {
  __builtin_amdgcn_global_load_lds(
      (const __attribute__((address_space(1))) unsigned int*)g,
      (__attribute__((address_space(3))) unsigned int*)l, 16, 0, 0);
}

// ---------------- Router: fp32 exact, one wave per token ----------------
__global__ void router_kernel(const float* __restrict__ x, const float* __restrict__ rk,
                              int* __restrict__ counts, int* __restrict__ tok_e,
                              float* __restrict__ tok_w) {
  int w = threadIdx.x >> 6, lane = threadIdx.x & 63;
  int t = blockIdx.x * 4 + w;
  float acc[NEXP];
#pragma unroll
  for (int e = 0; e < NEXP; ++e) acc[e] = 0.f;
  const float4* xr = (const float4*)(x + (size_t)t * DIM);
#pragma unroll
  for (int i = 0; i < 4; ++i) {
    float4 xv = xr[i * 64 + lane];
    int d0 = (i * 64 + lane) * 4;
#pragma unroll
    for (int j = 0; j < 4; ++j) {
      const float4* rr = (const float4*)(rk + (size_t)(d0 + j) * NEXP);
      float4 r0 = rr[0], r1 = rr[1];
      float xs = (j == 0) ? xv.x : (j == 1) ? xv.y : (j == 2) ? xv.z : xv.w;
      acc[0] += xs * r0.x; acc[1] += xs * r0.y; acc[2] += xs * r0.z; acc[3] += xs * r0.w;
      acc[4] += xs * r1.x; acc[5] += xs * r1.y; acc[6] += xs * r1.z; acc[7] += xs * r1.w;
    }
  }
#pragma unroll
  for (int off = 32; off > 0; off >>= 1) {
#pragma unroll
    for (int e = 0; e < NEXP; ++e) acc[e] += __shfl_xor(acc[e], off, 64);
  }
  if (lane == 0) {
    float m = acc[0];
    for (int e = 1; e < NEXP; ++e) m = fmaxf(m, acc[e]);
    float p[NEXP], s = 0.f;
    for (int e = 0; e < NEXP; ++e) { p[e] = expf(acc[e] - m); s += p[e]; }
    float inv = 1.f / s;
    for (int e = 0; e < NEXP; ++e) p[e] *= inv;
    int i1 = 0;
    for (int e = 1; e < NEXP; ++e) if (p[e] > p[i1]) i1 = e;      // ties -> lowest idx
    int i2 = (i1 == 0) ? 1 : 0;
    for (int e = 0; e < NEXP; ++e) if (e != i1 && p[e] > p[i2]) i2 = e;
    // reference: softmax over the two top PROBABILITIES
    float e1 = expf(p[i1]), e2 = expf(p[i2]);
    float winv = 1.f / (e1 + e2);
    tok_e[t * 2] = i1; tok_e[t * 2 + 1] = i2;
    tok_w[t * 2] = e1 * winv; tok_w[t * 2 + 1] = e2 * winv;
    atomicAdd(&counts[i1], 1); atomicAdd(&counts[i2], 1);
  }
}

__global__ void scan_kernel(const int* __restrict__ counts, int* __restrict__ offsets) {
  if (threadIdx.x == 0) {
    int s = 0;
    for (int e = 0; e < NEXP; ++e) { offsets[e] = s; s += counts[e]; }
  }
}

__global__ void assign_kernel(const int* __restrict__ tok_e, const float* __restrict__ tok_w,
                              const int* __restrict__ offsets, int* __restrict__ cursor,
                              int* __restrict__ slot_token, float* __restrict__ slot_weight,
                              int* __restrict__ tok_slot) {
  int t = blockIdx.x * 256 + threadIdx.x;
  if (t >= T_TOK) return;
#pragma unroll
  for (int k = 0; k < 2; ++k) {
    int e = tok_e[t * 2 + k];
    int pos = atomicAdd(&cursor[e], 1);
    int slot = offsets[e] + pos;
    slot_token[slot] = t;
    slot_weight[slot] = tok_w[t * 2 + k];
    tok_slot[t * 2 + k] = slot;
  }
}

// ---------------- Conversions ----------------
__global__ void cvt_x_kernel(const float* __restrict__ x, unsigned short* __restrict__ xb) {
  int i = blockIdx.x * 256 + threadIdx.x;  // T*D/8 threads
  const float4* p = (const float4*)x;
  float4 a = p[i * 2], b = p[i * 2 + 1];
  uint4 o;
  o.x = ((unsigned)f2bf(a.y) << 16) | f2bf(a.x);
  o.y = ((unsigned)f2bf(a.w) << 16) | f2bf(a.z);
  o.z = ((unsigned)f2bf(b.y) << 16) | f2bf(b.x);
  o.w = ((unsigned)f2bf(b.w) << 16) | f2bf(b.z);
  ((uint4*)xb)[i] = o;
}

// in fp32 [E][R][C] -> out bf16 [E][C][R]
__global__ void transpose_cvt_kernel(const float* __restrict__ in, unsigned short* __restrict__ out,
                                     int R, int C) {
  __shared__ float lds[64][65];
  int e = blockIdx.z;
  size_t base = (size_t)e * (size_t)R * (size_t)C;
  int rb = blockIdx.y * 64, cb = blockIdx.x * 64;
  int tid = threadIdx.x;
  int col4 = (tid & 15) * 4, row = tid >> 4;
#pragma unroll
  for (int it = 0; it < 4; ++it) {
    int r = row + it * 16;
    float4 v = *(const float4*)(in + base + (size_t)(rb + r) * C + cb + col4);
    lds[col4 + 0][r] = v.x; lds[col4 + 1][r] = v.y;
    lds[col4 + 2][r] = v.z; lds[col4 + 3][r] = v.w;
  }
  __syncthreads();
  int r2 = (tid & 31) * 2, c = tid >> 5;
#pragma unroll
  for (int it = 0; it < 8; ++it) {
    int cc = c + it * 8;
    unsigned v = ((unsigned)f2bf(lds[cc][r2 + 1]) << 16) | f2bf(lds[cc][r2]);
    *(unsigned*)(out + base + (size_t)(cb + cc) * R + rb + r2) = v;
  }
}

// LDS XOR-swizzle (T2, rule #21): linear gld_lds dest + permuted GLOBAL source chunk
// + matching XOR on the ds_read side. Tile is [128 rows][64 cols] bf16 (8 chunks of
// 8 bf16 per row). Stored chunk kc of row r holds global chunk kc ^ (r&7).
// Staging instr i covers rows i*8+(lane>>3), chunk lane&7 -> source chunk
// (lane&7)^(lane>>3). Fragment read at logical kof XORs ((row&7)<<3) where
// row&7 == lane&7 for all q (wr, q*16 are multiples of 8).

// ---------------- Pass A: fuse[slot][F] = silu(X@Wg) * (X@Wu), grouped per expert ----------------
__global__ __launch_bounds__(256) void gemm_gateup(
    const unsigned short* __restrict__ xb, const unsigned short* __restrict__ wg,
    const unsigned short* __restrict__ wu, const int* __restrict__ counts,
    const int* __restrict__ offsets, const int* __restrict__ slot_token,
    unsigned short* __restrict__ fuse) {
  int e = blockIdx.z;
  int cnt = counts[e];
  int mt = blockIdx.y;
  if (mt * 128 >= cnt) return;
  int off = offsets[e];
  int nt = blockIdx.x;
  __shared__ unsigned short Al[128 * 64];
  __shared__ unsigned short Bgl[128 * 64];
  __shared__ unsigned short Bul[128 * 64];
  int tid = threadIdx.x, w = tid >> 6, lane = tid & 63;
  int w4 = w * 4;
  int csrc = ((lane & 7) ^ (lane >> 3)) * 8;  // swizzled source chunk (bf16 elems)
  const unsigned short* asrc[4];
  const unsigned short* bgsrc[4];
  const unsigned short* busrc[4];
#pragma unroll
  for (int ii = 0; ii < 4; ++ii) {
    int i = w4 + ii;
    int r = i * 8 + (lane >> 3);
    int row = mt * 128 + r;
    int tok = (row < cnt) ? slot_token[off + row] : 0;  // clamp: garbage rows computed, not written
    asrc[ii] = xb + (size_t)tok * DIM + csrc;
    size_t frow = (size_t)e * FDIM + (size_t)(nt * 128 + r);
    bgsrc[ii] = wg + frow * DIM + csrc;
    busrc[ii] = wu + frow * DIM + csrc;
  }
  f32x4 accg[4][4] = {};
  f32x4 accu[4][4] = {};
  int wr = (w >> 1) * 64, wc = (w & 1) * 64;
  int swz = (lane & 7) << 3;
  int kof0 = ((lane >> 4) * 8) ^ swz;        // kk=0 swizzled col offset
  int kof1 = (32 + (lane >> 4) * 8) ^ swz;   // kk=1
  for (int k0 = 0; k0 < DIM; k0 += 64) {
#pragma unroll
    for (int ii = 0; ii < 4; ++ii) {
      int i = w4 + ii;
      gld_lds16(asrc[ii] + k0, &Al[i * 512]);
      gld_lds16(bgsrc[ii] + k0, &Bgl[i * 512]);
      gld_lds16(busrc[ii] + k0, &Bul[i * 512]);
    }
    __syncthreads();
#pragma unroll
    for (int kk = 0; kk < 2; ++kk) {
      int kof = kk ? kof1 : kof0;
      bf16x8 af[4], bg[4], bu[4];
#pragma unroll
      for (int q = 0; q < 4; ++q) {
        af[q] = *(const bf16x8*)&Al[(wr + q * 16 + (lane & 15)) * 64 + kof];
        bg[q] = *(const bf16x8*)&Bgl[(wc + q * 16 + (lane & 15)) * 64 + kof];
        bu[q] = *(const bf16x8*)&Bul[(wc + q * 16 + (lane & 15)) * 64 + kof];
      }
#pragma unroll
      for (int m4 = 0; m4 < 4; ++m4) {
#pragma unroll
        for (int n4 = 0; n4 < 4; ++n4) {
          accg[m4][n4] = __builtin_amdgcn_mfma_f32_16x16x32_bf16(af[m4], bg[n4], accg[m4][n4], 0, 0, 0);
          accu[m4][n4] = __builtin_amdgcn_mfma_f32_16x16x32_bf16(af[m4], bu[n4], accu[m4][n4], 0, 0, 0);
        }
      }
    }
    __syncthreads();
  }
#pragma unroll
  for (int m4 = 0; m4 < 4; ++m4) {
#pragma unroll
    for (int n4 = 0; n4 < 4; ++n4) {
      f32x4 g = accg[m4][n4], u = accu[m4][n4];
#pragma unroll
      for (int j = 0; j < 4; ++j) {
        int r = wr + m4 * 16 + (lane >> 4) * 4 + j;  // C layout: row=(lane>>4)*4+reg
        int row = mt * 128 + r;
        if (row < cnt) {
          float gv = g[j];
          float val = gv / (1.f + expf(-gv)) * u[j];
          int f = nt * 128 + wc + n4 * 16 + (lane & 15);  // col=lane&15
          fuse[(size_t)(off + row) * FDIM + f] = f2bf(val);
        }
      }
    }
  }
}

// ---------------- Pass B: part[slot][D] = w_slot * (fuse @ WdT) ----------------
__global__ __launch_bounds__(256) void gemm_down(
    const unsigned short* __restrict__ fuse, const unsigned short* __restrict__ wd,
    const int* __restrict__ counts, const int* __restrict__ offsets,
    const float* __restrict__ slot_weight, float* __restrict__ part) {
  int e = blockIdx.z;
  int cnt = counts[e];
  int mt = blockIdx.y;
  if (mt * 128 >= cnt) return;
  int off = offsets[e];
  int nt = blockIdx.x;  // over D/128 = 8
  __shared__ unsigned short Al[128 * 64];
  __shared__ unsigned short Bl[128 * 64];
  int tid = threadIdx.x, w = tid >> 6, lane = tid & 63;
  int w4 = w * 4;
  int csrc = ((lane & 7) ^ (lane >> 3)) * 8;
  const unsigned short* asrc[4];
  const unsigned short* bsrc[4];
#pragma unroll
  for (int ii = 0; ii < 4; ++ii) {
    int i = w4 + ii;
    int r = i * 8 + (lane >> 3);
    int row = mt * 128 + r;
    int grow = (row < cnt) ? (off + row) : off;  // clamp to valid memory
    asrc[ii] = fuse + (size_t)grow * FDIM + csrc;
    size_t drow = (size_t)e * DIM + (size_t)(nt * 128 + r);
    bsrc[ii] = wd + drow * FDIM + csrc;
  }
  f32x4 acc[4][4] = {};
  int wr = (w >> 1) * 64, wc = (w & 1) * 64;
  int swz = (lane & 7) << 3;
  int kof0 = ((lane >> 4) * 8) ^ swz;
  int kof1 = (32 + (lane >> 4) * 8) ^ swz;
  for (int k0 = 0; k0 < FDIM; k0 += 64) {
#pragma unroll
    for (int ii = 0; ii < 4; ++ii) {
      int i = w4 + ii;
      gld_lds16(asrc[ii] + k0, &Al[i * 512]);
      gld_lds16(bsrc[ii] + k0, &Bl[i * 512]);
    }
    __syncthreads();
#pragma unroll
    for (int kk = 0; kk < 2; ++kk) {
      int kof = kk ? kof1 : kof0;
      bf16x8 af[4], bfr[4];
#pragma unroll
      for (int q = 0; q < 4; ++q) {
        af[q] = *(const bf16x8*)&Al[(wr + q * 16 + (lane & 15)) * 64 + kof];
        bfr[q] = *(const bf16x8*)&Bl[(wc + q * 16 + (lane & 15)) * 64 + kof];
      }
#pragma unroll
      for (int m4 = 0; m4 < 4; ++m4) {
#pragma unroll
        for (int n4 = 0; n4 < 4; ++n4) {
          acc[m4][n4] = __builtin_amdgcn_mfma_f32_16x16x32_bf16(af[m4], bfr[n4], acc[m4][n4], 0, 0, 0);
        }
      }
    }
    __syncthreads();
  }
#pragma unroll
  for (int m4 = 0; m4 < 4; ++m4) {
#pragma unroll
    for (int j = 0; j < 4; ++j) {
      int r = wr + m4 * 16 + (lane >> 4) * 4 + j;
      int row = mt * 128 + r;
      if (row < cnt) {
        float wgt = slot_weight[off + row];
#pragma unroll
        for (int n4 = 0; n4 < 4; ++n4) {
          int d = nt * 128 + wc + n4 * 16 + (lane & 15);
          part[(size_t)(off + row) * DIM + d] = acc[m4][n4][j] * wgt;
        }
      }
    }
  }
}

// ---------------- Combine: out[t] = part[slot0] + part[slot1] ----------------
__global__ void combine_kernel(const float* __restrict__ part, const int* __restrict__ tok_slot,
                               float* __restrict__ out) {
  int i = blockIdx.x * 256 + threadIdx.x;  // T*D/4 threads
  int t = i >> 8;
  int c = i & 255;
  int s0 = tok_slot[t * 2], s1 = tok_slot[t * 2 + 1];
  float4 a = ((const float4*)(part + (size_t)s0 * DIM))[c];
  float4 b = ((const float4*)(part + (size_t)s1 * DIM))[c];
  float4 o;
  o.x = a.x + b.x; o.y = a.y + b.y; o.z = a.z + b.z; o.w = a.w + b.w;
  ((float4*)(out + (size_t)t * DIM))[c] = o;
}

extern "C" void kernel_launch(void* const* d_in, const int* in_sizes, int n_in,
                              void* d_out, int out_size, void* d_ws, size_t ws_size,
                              hipStream_t stream) {
  (void)in_sizes; (void)n_in; (void)out_size;
  const float* x    = (const float*)d_in[0];
  const float* rk   = (const float*)d_in[1];
  const float* wg_f = (const float*)d_in[2];
  const float* wu_f = (const float*)d_in[3];
  const float* wd_f = (const float*)d_in[4];
  float* out = (float*)d_out;

  char* ws = (char*)d_ws;
  size_t o_xb   = 0;
  size_t o_wg   = o_xb + (size_t)T_TOK * DIM * 2;
  size_t o_wu   = o_wg + (size_t)NEXP * FDIM * DIM * 2;
  size_t o_wd   = o_wu + (size_t)NEXP * FDIM * DIM * 2;
  size_t o_fuse = o_wd + (size_t)NEXP * DIM * FDIM * 2;
  size_t o_part = o_fuse + (size_t)NSLOT * FDIM * 2;
  size_t o_meta = o_part + (size_t)NSLOT * DIM * 4;
  size_t o_counts = o_meta;
  size_t o_cursor = o_counts + 32;
  size_t o_offs   = o_cursor + 32;
  size_t o_tok_e  = o_offs + 32;
  size_t o_tok_w  = o_tok_e + (size_t)T_TOK * 2 * 4;
  size_t o_tok_s  = o_tok_w + (size_t)T_TOK * 2 * 4;
  size_t o_st     = o_tok_s + (size_t)T_TOK * 2 * 4;
  size_t o_sw     = o_st + (size_t)NSLOT * 4;
  size_t need     = o_sw + (size_t)NSLOT * 4;
  if (ws_size < need) return;  // diagnostic: absmax will equal ~0.785 (zero output)

  unsigned short* xb   = (unsigned short*)(ws + o_xb);
  unsigned short* wgt  = (unsigned short*)(ws + o_wg);
  unsigned short* wut  = (unsigned short*)(ws + o_wu);
  unsigned short* wdt  = (unsigned short*)(ws + o_wd);
  unsigned short* fuse = (unsigned short*)(ws + o_fuse);
  float* part          = (float*)(ws + o_part);
  int* counts          = (int*)(ws + o_counts);
  int* cursor          = (int*)(ws + o_cursor);
  int* offsets         = (int*)(ws + o_offs);
  int* tok_e           = (int*)(ws + o_tok_e);
  float* tok_w         = (float*)(ws + o_tok_w);
  int* tok_slot        = (int*)(ws + o_tok_s);
  int* slot_token      = (int*)(ws + o_st);
  float* slot_weight   = (float*)(ws + o_sw);

  hipMemsetAsync(ws + o_counts, 0, 64, stream);  // counts + cursor
  router_kernel<<<T_TOK / 4, 256, 0, stream>>>(x, rk, counts, tok_e, tok_w);
  scan_kernel<<<1, 64, 0, stream>>>(counts, offsets);
  assign_kernel<<<T_TOK / 256, 256, 0, stream>>>(tok_e, tok_w, offsets, cursor,
                                                 slot_token, slot_weight, tok_slot);
  cvt_x_kernel<<<(T_TOK * DIM / 8) / 256, 256, 0, stream>>>(x, xb);
  transpose_cvt_kernel<<<dim3(FDIM / 64, DIM / 64, NEXP), 256, 0, stream>>>(wg_f, wgt, DIM, FDIM);
  transpose_cvt_kernel<<<dim3(FDIM / 64, DIM / 64, NEXP), 256, 0, stream>>>(wu_f, wut, DIM, FDIM);
  transpose_cvt_kernel<<<dim3(DIM / 64, FDIM / 64, NEXP), 256, 0, stream>>>(wd_f, wdt, FDIM, DIM);
  gemm_gateup<<<dim3(FDIM / 128, 16, NEXP), 256, 0, stream>>>(xb, wgt, wut, counts, offsets,
                                                              slot_token, fuse);
  gemm_down<<<dim3(DIM / 128, 16, NEXP), 256, 0, stream>>>(fuse, wdt, counts, offsets,
                                                           slot_weight, part);
  combine_kernel<<<(T_TOK * DIM / 4) / 256, 256, 0, stream>>>(part, tok_slot, out);
}